// Round 6
// baseline (52.397 us; speedup 1.0000x reference)
//
#include <hip/hip_runtime.h>
#include <hip/hip_bf16.h>
#include <math.h>

// Problem constants (B, NA, NO, D, C, T) = (2048, 64, 64, 128, 64, 3)
#define NB 2048
#define NNODES 129
#define ND 128
#define NC 64

typedef unsigned int u32;

// ws float layout:
//  [0]              : mask-dtype flag (int)
//  [16 .. 16+1152)  : u[j*3+i][d]  (9 x 128)   u = W[j] @ a1[i]
//  [1168 .. +384)   : v2[i][d]     (3 x 128)   v2 = W[i] @ a2[i]

__device__ __forceinline__ bool mask_at(const void* m, int flag, int idx) {
  if (flag == 1) return ((const unsigned char*)m)[idx] != 0;
  if (flag == 2) return ((const float*)m)[idx] != 0.0f;
  return ((const int*)m)[idx] != 0;
}

__device__ __forceinline__ u32 pack2bf(float a, float b) {
  __hip_bfloat162 p = __float22bfloat162_rn(make_float2(a, b));  // v_cvt_pk_bf16_f32
  u32 w;
  __builtin_memcpy(&w, &p, 4);
  return w;
}
__device__ __forceinline__ float2 unpack2bf(u32 w) {
  float lo = __builtin_bit_cast(float, w << 16);
  float hi = __builtin_bit_cast(float, w & 0xffff0000u);
  return make_float2(lo, hi);
}

__global__ void hetgat_precomp(const float* __restrict__ W, const float* __restrict__ a,
                               const void* __restrict__ mask, float* __restrict__ ws) {
  int gidx = blockIdx.x * 256 + threadIdx.x;
  if (blockIdx.x == 6) {
    if (threadIdx.x == 0) {
      const unsigned char* mb = (const unsigned char*)mask;
      const unsigned int* mw = (const unsigned int*)mask;
      bool bytes01 = true, words01 = true, wordsF = true;
      for (int i = 0; i < 256; ++i) { if (mb[i] > 1) bytes01 = false; }
      for (int i = 0; i < 64; ++i) {
        unsigned int w = mw[i];
        if (w != 0u && w != 1u) words01 = false;
        if (w != 0u && w != 0x3F800000u) wordsF = false;
      }
      int flag;
      if (words01) flag = 0;
      else if (bytes01) flag = 1;
      else if (wordsF) flag = 2;
      else flag = 1;
      ((int*)ws)[0] = flag;
    }
    return;
  }
  if (gidx < 1152) {                // u[j*3+i][d]
    int ji = gidx >> 7, d = gidx & 127;
    int j = ji / 3, i = ji - 3 * j;
    const float4* Wp = (const float4*)(W + j * 8192 + d * 64);
    const float4* ap = (const float4*)(a + i * 128);
    float s = 0.f;
#pragma unroll
    for (int c = 0; c < 16; ++c) {
      float4 w4 = Wp[c], a4 = ap[c];
      s += w4.x * a4.x + w4.y * a4.y + w4.z * a4.z + w4.w * a4.w;
    }
    ws[16 + gidx] = s;
  } else if (gidx < 1536) {         // v2[i][d]
    int rel = gidx - 1152;
    int i = rel >> 7, d = rel & 127;
    const float4* Wp = (const float4*)(W + i * 8192 + d * 64);
    const float4* ap = (const float4*)(a + i * 128 + 64);
    float s = 0.f;
#pragma unroll
    for (int c = 0; c < 16; ++c) {
      float4 w4 = Wp[c], a4 = ap[c];
      s += w4.x * a4.x + w4.y * a4.y + w4.z * a4.z + w4.w * a4.w;
    }
    ws[1168 + rel] = s;
  }
}

// LDS float-offsets. hl: 129 rows x 64 u32 (bf16x2), 16B-chunk XOR swizzle by (row&7).
#define OFF_WA   8256   // 192
#define OFF_WO   8448   // 192
#define OFF_MSF  8640   // 4
#define OFF_ESW  8644   // 32  (2 waves x 16)
#define OFF_ERA  8676   // 192  (union: gl[384] spans era+ero after softmax)
#define OFF_ERO  8868   // 192
#define OFF_V2L  9060   // 384  (union: red[256] in epilogue)
#define OFF_GL   8676
#define OFF_RED  9060
#define LDS_FLOATS 9444  // 37,776 B -> 4 blocks/CU

__global__ __launch_bounds__(256, 4) void hetgat_main(
    const float* __restrict__ h, const float* __restrict__ W,
    const void* __restrict__ mask, const float* __restrict__ ws,
    float* __restrict__ out) {
  __shared__ float lds[LDS_FLOATS];
  u32* hlu   = (u32*)lds;
  float* wa  = lds + OFF_WA;
  float* wo  = lds + OFF_WO;
  float* msf = lds + OFF_MSF;
  float* esw = lds + OFF_ESW;
  float* era = lds + OFF_ERA;
  float* ero = lds + OFF_ERO;
  float* v2l = lds + OFF_V2L;
  float* gl  = lds + OFF_GL;
  float* red = lds + OFF_RED;

  const int b = blockIdx.x;
  const int tid = threadIdx.x;
  const int wv = tid >> 6, ln = tid & 63;
  const int flag = ((const int*)ws)[0];
  const float* __restrict__ hb = h + (size_t)b * NNODES * ND;

  // ---- entry: prefetch masks into registers ----
  bool mreg0 = false, mreg1 = false, mreg2 = false;
  float msreg = 0.f;
  if (wv == 0) {
    int base = b * NNODES + 1 + ln;
    mreg0 = mask_at(mask, flag, 0 * NB * NNODES + base);
    mreg1 = mask_at(mask, flag, 1 * NB * NNODES + base);
    mreg2 = mask_at(mask, flag, 2 * NB * NNODES + base);
  } else if (wv == 1) {
    int base = b * NNODES + 65 + ln;
    mreg0 = mask_at(mask, flag, 0 * NB * NNODES + base);
    mreg1 = mask_at(mask, flag, 1 * NB * NNODES + base);
    mreg2 = mask_at(mask, flag, 2 * NB * NNODES + base);
  } else if (wv == 2 && ln < 3) {
    msreg = mask_at(mask, flag, (ln * NB + b) * NNODES) ? 1.f : 0.f;
  }

  // ---- phase A: fused stage + logits. pair (2k,2k+1) owns row k+1 ----
  const int half = tid & 1;
  const int row = (tid >> 1) + 1;            // 1..128
  const float4* hp = (const float4*)(hb + row * ND + half * 64);
  float4 hreg[16];
#pragma unroll
  for (int q = 0; q < 16; ++q) hreg[q] = hp[q];   // issue all half-row loads

  if (tid < 96) ((float4*)v2l)[tid] = ((const float4*)(ws + 1168))[tid];
  if (wv == 2 && ln < 3) msf[ln] = msreg;
  __syncthreads();                            // publishes v2l (h loads still in flight)

  // 3 half-dots vs v2 (parity-broadcast LDS reads, conflict-free)
  float a0 = 0.f, a1 = 0.f, a2 = 0.f;
  {
    const float4* vf = (const float4*)v2l + half * 16;
#pragma unroll
    for (int q = 0; q < 16; ++q) {
      float4 x = hreg[q];
      float4 p0 = vf[q], p1 = vf[32 + q], p2 = vf[64 + q];
      a0 += x.x * p0.x + x.y * p0.y + x.z * p0.z + x.w * p0.w;
      a1 += x.x * p1.x + x.y * p1.y + x.z * p1.z + x.w * p1.w;
      a2 += x.x * p2.x + x.y * p2.y + x.z * p2.z + x.w * p2.w;
    }
  }
  // pack own half-row to bf16 and store swizzled
  {
    const int s = row & 7;
#pragma unroll
    for (int k2 = 0; k2 < 8; ++k2) {
      float4 u = hreg[2 * k2], v = hreg[2 * k2 + 1];
      uint4 w;
      w.x = pack2bf(u.x, u.y); w.y = pack2bf(u.z, u.w);
      w.z = pack2bf(v.x, v.y); w.w = pack2bf(v.z, v.w);
      *(uint4*)(hlu + row * 64 + (((8 * half + k2) ^ s) << 2)) = w;
    }
  }
  // combine half-dots with partner; even lane writes raw logits
  a0 += __shfl_xor(a0, 1);
  a1 += __shfl_xor(a1, 1);
  a2 += __shfl_xor(a2, 1);
  if (half == 0) {
    if (row <= 64) {
      era[row - 1] = a0; era[64 + row - 1] = a1; era[128 + row - 1] = a2;
    } else {
      ero[row - 65] = a0; ero[64 + row - 65] = a1; ero[128 + row - 65] = a2;
    }
  }
  // threads 0,1 additionally stage row 0 (self) — swizzle identity
  if (tid < 2) {
    const float4* sp = (const float4*)(hb + half * 64);
#pragma unroll
    for (int k2 = 0; k2 < 8; ++k2) {
      float4 u = sp[2 * k2], v = sp[2 * k2 + 1];
      uint4 w;
      w.x = pack2bf(u.x, u.y); w.y = pack2bf(u.z, u.w);
      w.z = pack2bf(v.x, v.y); w.w = pack2bf(v.z, v.w);
      *(uint4*)(hlu + ((8 * half + k2) << 2)) = w;
    }
  }
  __syncthreads();

  // ---- phase B: e_self (lanes 0-8, per softmax wave) + collapsed softmax ----
  if (wv < 2) {
    if (ln < 9) {                          // es[j*3+i] = h_self . u[j,i]
      const float4* uu = (const float4*)(ws + 16 + (ln << 7));
      const uint4* r0 = (const uint4*)hlu; // row 0
      float s = 0.f;
#pragma unroll 4
      for (int ch = 0; ch < 16; ++ch) {
        uint4 x = r0[ch];
        float4 u0 = uu[2 * ch], u1 = uu[2 * ch + 1];
        float2 f0 = unpack2bf(x.x), f1 = unpack2bf(x.y), f2 = unpack2bf(x.z), f3 = unpack2bf(x.w);
        s += f0.x * u0.x + f0.y * u0.y + f1.x * u0.z + f1.y * u0.w
           + f2.x * u1.x + f2.y * u1.y + f3.x * u1.z + f3.y * u1.w;
      }
      esw[wv * 16 + ln] = s;               // within-wave LDS write->read, no barrier
    }
    const float* e = (wv == 0) ? era : ero;
    float* w = (wv == 0) ? wa : wo;
    const float* es = esw + wv * 16;
    float ms[3], S[3];
#pragma unroll
    for (int i = 0; i < 3; ++i) {
      float e0 = es[i], e1 = es[3 + i], e2 = es[6 + i];
      float m = fmaxf(fmaxf(e0, e1), e2);
      ms[i] = m;
      S[i] = __expf(e0 - m) + __expf(e1 - m) + __expf(e2 - m);
    }
    float v0  = mreg0 ? -INFINITY : e[ln];
    float v1  = mreg1 ? -INFINITY : e[64 + ln];
    float v2v = mreg2 ? -INFINITY : e[128 + ln];
    float c0 = v0 + ms[0], c1 = v1 + ms[1], c2 = v2v + ms[2];
    float mx = fmaxf(fmaxf(c0, c1), c2);
    for (int off = 32; off; off >>= 1) mx = fmaxf(mx, __shfl_xor(mx, off));
    float t0 = 0.f, t1 = 0.f, t2 = 0.f;
    if (mx != -INFINITY) {
      t0 = mreg0 ? 0.f : S[0] * __expf(c0 - mx);
      t1 = mreg1 ? 0.f : S[1] * __expf(c1 - mx);
      t2 = mreg2 ? 0.f : S[2] * __expf(c2 - mx);
    }
    float z = t0 + t1 + t2;
    for (int off = 32; off; off >>= 1) z += __shfl_xor(z, off);
    float inv = (z > 0.f) ? 1.f / z : 0.f;
    w[ln] = t0 * inv; w[64 + ln] = t1 * inv; w[128 + ln] = t2 * inv;
  }
  __syncthreads();

  // ---- phase C: g[t][d] = msf_t*h_self[d] + sum_n w[t,n]*h_node[n,d]  (wave = type) ----
  if (wv < 3) {
    const int l2 = ln;                       // owns d-pair (2*l2, 2*l2+1)
    float2 fs = unpack2bf(hlu[l2]);          // row 0: swizzle identity
    float m = msf[wv];
    float g0 = m * fs.x, g1 = m * fs.y;
    const float* wap = wa + wv * 64;
    const float* wop = wo + wv * 64;
    const int chh = l2 >> 2, sub = l2 & 3;
#pragma unroll 8
    for (int n = 0; n < 64; ++n) {
      int rA = 1 + n, rO = 65 + n;
      float2 fA = unpack2bf(hlu[rA * 64 + ((chh ^ (rA & 7)) << 2) + sub]);
      float2 fO = unpack2bf(hlu[rO * 64 + ((chh ^ (rO & 7)) << 2) + sub]);
      float wA = wap[n], wO = wop[n];
      g0 += wA * fA.x + wO * fO.x;
      g1 += wA * fA.y + wO * fO.y;
    }
    gl[wv * ND + 2 * l2] = g0;
    gl[wv * ND + 2 * l2 + 1] = g1;
  }
  __syncthreads();

  // ---- phase D: epilogue out[b,c] = elu( sum_t g[t] @ W[t][:,c] ) ----
  {
    int q = tid >> 6, c = tid & 63;
    float acc = 0.f;
#pragma unroll
    for (int t = 0; t < 3; ++t) {
      const float* gp = gl + t * ND;
      const float* Wp = W + t * 8192 + c;
#pragma unroll 8
      for (int dd = 32 * q; dd < 32 * q + 32; ++dd) {
        acc += gp[dd] * Wp[dd * 64];
      }
    }
    red[q * 64 + c] = acc;
  }
  __syncthreads();
  if (tid < 64) {
    float x = red[tid] + red[64 + tid] + red[128 + tid] + red[192 + tid];
    out[(size_t)b * NC + tid] = (x > 0.f) ? x : expm1f(x);
  }
}

extern "C" void kernel_launch(void* const* d_in, const int* in_sizes, int n_in,
                              void* d_out, int out_size, void* d_ws, size_t ws_size,
                              hipStream_t stream) {
  (void)in_sizes; (void)n_in; (void)out_size; (void)ws_size;
  const float* h   = (const float*)d_in[0];
  const float* W   = (const float*)d_in[1];
  const float* a   = (const float*)d_in[2];
  const void* mask = d_in[3];
  float* ws  = (float*)d_ws;
  float* out = (float*)d_out;

  hetgat_precomp<<<dim3(7), dim3(256), 0, stream>>>(W, a, mask, ws);
  hetgat_main<<<dim3(NB), dim3(256), 0, stream>>>(h, W, mask, ws, out);
}